// Round 14
// baseline (1756.237 us; speedup 1.0000x reference)
//
#include <hip/hip_runtime.h>
#include <hip/hip_bf16.h>
#include <stdint.h>

#define S_NUM 50000
#define E_NUM 20000
#define NNODE 70000
#define KDIM 128
#define BATCH 8192
#define NEDGE 1000000

#define NRANGE 128            // dst-ranges per graph
#define RSZ 547               // ceil(NNODE / NRANGE)
#define BUCKET_CAP 8448       // per-bucket capacity (mean 7813, sigma 88)
#define RCAP 16672            // per-range padded csr region, mult of 16
#define CHUNK 8192            // edges per bucket_k block
#define BINCAP 120            // LDS bin capacity
#define GR 256                // gemm rows per block
#define CAPC 16384            // max compacted L3 nodes (2*BATCH)
#define NT 8                  // column tiles (16 dims each) -> 2.24MB plane < 4MB L2
#define TDIM 16
#define CH 128                // nodes per queue-chunk claim

typedef __attribute__((ext_vector_type(8))) short short8;
typedef __attribute__((ext_vector_type(4))) float f32x4;
typedef __attribute__((ext_vector_type(2))) float f32x2;
typedef __attribute__((ext_vector_type(4))) uint32_t u32x4;

__device__ __forceinline__ float bf2f(ushort u) {
    union { uint32_t i; float f; } v; v.i = ((uint32_t)u) << 16; return v.f;
}
__device__ __forceinline__ ushort f2bf(float f) {
    union { uint32_t i; float f; } v; v.f = f;
    uint32_t r = v.i + 0x7fffu + ((v.i >> 16) & 1u);
    return (ushort)(r >> 16);
}
__device__ __forceinline__ f32x2 up2(uint32_t u) {
    union { uint32_t i; float f; } lo, hi;
    lo.i = u << 16; hi.i = u & 0xffff0000u;
    f32x2 r; r.x = lo.f; r.y = hi.f; return r;
}
__device__ __forceinline__ uint32_t pk2(f32x2 a) {
    return (uint32_t)f2bf(a.x) | ((uint32_t)f2bf(a.y) << 16);
}

// tiled feature arrays: [NT][(NNODE+1)][TDIM] bf16
#define PLANE_E ((size_t)(NNODE + 1) * TDIM)
#define PLANE_U4 ((size_t)(NNODE + 1) * 2)

// ---------------- W prep (+ zero gbcnt/flags/nsel/qcur): bf16 hi/lo split, swizzled --------
__global__ void prepW_k(const float* __restrict__ rW, const float* __restrict__ wW,
                        ushort* __restrict__ ws, int* __restrict__ gbcnt,
                        int* __restrict__ flags, int* __restrict__ nsel,
                        int* __restrict__ qcur) {
    int t = blockIdx.x * blockDim.x + threadIdx.x;
    if (blockIdx.x == 0 && threadIdx.x < 256) gbcnt[threadIdx.x] = 0;
    if (blockIdx.x == 0 && threadIdx.x < 48) qcur[threadIdx.x] = 0;
    if (t == 0) nsel[0] = 0;
    if (t < NNODE) flags[t] = 0;
    if (t >= 6 * 16384) return;
    int m = t >> 14, idx = t & 16383;
    const float* W = (m < 3) ? rW + m * 16384 : wW + (m - 3) * 16384;
    float x = W[idx];
    int k = idx >> 7, c = idx & 127;
    ushort hb = f2bf(x);
    ushort lb = f2bf(x - bf2f(hb));
    int off = ((c * 256 + 2 * k) ^ ((c & 7) << 4)) >> 1;
    ws[(size_t)m * 32768 + off] = hb;
    ws[(size_t)m * 32768 + 16384 + off] = lb;
}

// ---------------- pass 1: bin edges by dst-range, packed (local_dst<<17 | src) -------------
__global__ __launch_bounds__(256) void bucket_k(const int* __restrict__ redge,
                                                const int* __restrict__ wedge,
                                                int* __restrict__ gbcnt,
                                                uint32_t* __restrict__ bpk) {
    __shared__ uint32_t lpk[NRANGE][BINCAP];
    __shared__ int lcnt[NRANGE];
    __shared__ int gbase[NRANGE];
    const int NB = (NEDGE + CHUNK - 1) / CHUNK;
    int bid = blockIdx.x;
    int graph = bid >= NB;
    int cb = graph ? bid - NB : bid;
    const int* eg = graph ? wedge : redge;
    int e0 = cb * CHUNK;
    int nthis = min(CHUNK, NEDGE - e0);
    for (int i = threadIdx.x; i < NRANGE; i += 256) lcnt[i] = 0;
    __syncthreads();
    for (int i = threadIdx.x; i < nthis; i += 256) {
        int s = eg[e0 + i];
        int d = eg[NEDGE + e0 + i];
        int b = d / RSZ;
        uint32_t p = ((uint32_t)(d - b * RSZ) << 17) | (uint32_t)s;
        int slot = atomicAdd(&lcnt[b], 1);
        if (slot < BINCAP) lpk[b][slot] = p;
        else {
            int gs = atomicAdd(&gbcnt[graph * NRANGE + b], 1);
            if (gs < BUCKET_CAP)
                bpk[(size_t)(graph * NRANGE + b) * BUCKET_CAP + gs] = p;
        }
    }
    __syncthreads();
    for (int b = threadIdx.x; b < NRANGE; b += 256) {
        int c = min(lcnt[b], BINCAP);
        lcnt[b] = c;
        gbase[b] = atomicAdd(&gbcnt[graph * NRANGE + b], c);
    }
    __syncthreads();
    for (int b = 0; b < NRANGE; ++b) {
        int c = lcnt[b];
        size_t base = (size_t)(graph * NRANGE + b) * BUCKET_CAP + gbase[b];
        for (int i = threadIdx.x; i < c; i += 256)
            if (gbase[b] + i < BUCKET_CAP) bpk[base + i] = lpk[b][i];
    }
}

// ---------------- pass 2: CSR slice in LDS, 16-padded rows, fixed per-combo regions --------
__global__ __launch_bounds__(256) void build_k(const uint32_t* __restrict__ bpk,
                                               const int* __restrict__ gbcnt,
                                               int* __restrict__ rpb,
                                               int* __restrict__ rpe,
                                               int* __restrict__ csr) {
    __shared__ int lcnt[RSZ];
    __shared__ int lexcl[RSZ];
    __shared__ int pexcl[RSZ];
    __shared__ int lcur[RSZ];
    __shared__ int sliceB[BUCKET_CAP];
    __shared__ int wsum[4];
    __shared__ int s_carry;
    int combo = blockIdx.x;                 // 0..255
    int graph = combo >> 7, grp = combo & (NRANGE - 1);
    int lo = grp * RSZ;
    int rsize = min(RSZ, NNODE - lo);
    int n = min(gbcnt[combo], BUCKET_CAP);
    const uint32_t* bp = bpk + (size_t)combo * BUCKET_CAP;
    int* rpbg = rpb + graph * NNODE;
    int* rpeg = rpe + graph * NNODE;
    int* og = csr + (size_t)combo * RCAP;
    const int rbase = combo * RCAP;
    int tid = threadIdx.x, lane = tid & 63, wid = tid >> 6;

    for (int i = tid; i < rsize; i += 256) lcnt[i] = 0;
    if (tid == 0) s_carry = 0;
    __syncthreads();
    for (int i = tid; i < n; i += 256)
        atomicAdd(&lcnt[bp[i] >> 17], 1);
    __syncthreads();
    // scan 1: real counts -> lexcl
    for (int base = 0; base < rsize; base += 256) {
        int i = base + tid;
        int v = (i < rsize) ? lcnt[i] : 0;
        int incl = v;
        #pragma unroll
        for (int off = 1; off < 64; off <<= 1) {
            int t = __shfl_up(incl, off, 64);
            if (lane >= off) incl += t;
        }
        if (lane == 63) wsum[wid] = incl;
        __syncthreads();
        int carry = s_carry;
        if (wid == 0 && lane < 4) {
            int wv = wsum[lane];
            #pragma unroll
            for (int off = 1; off < 4; off <<= 1) {
                int t = __shfl_up(wv, off, 64);
                if (lane >= off) wv += t;
            }
            wsum[lane] = wv;
        }
        __syncthreads();
        int waveoff = (wid == 0) ? 0 : wsum[wid - 1];
        int excl = carry + waveoff + incl - v;
        if (i < rsize) { lexcl[i] = excl; lcur[i] = excl; }
        __syncthreads();
        if (tid == 0) s_carry = carry + wsum[3];
        __syncthreads();
    }
    if (tid == 0) s_carry = 0;
    __syncthreads();
    // scan 2: padded counts -> pexcl
    for (int base = 0; base < rsize; base += 256) {
        int i = base + tid;
        int v = (i < rsize) ? ((lcnt[i] + 15) & ~15) : 0;
        int incl = v;
        #pragma unroll
        for (int off = 1; off < 64; off <<= 1) {
            int t = __shfl_up(incl, off, 64);
            if (lane >= off) incl += t;
        }
        if (lane == 63) wsum[wid] = incl;
        __syncthreads();
        int carry = s_carry;
        if (wid == 0 && lane < 4) {
            int wv = wsum[lane];
            #pragma unroll
            for (int off = 1; off < 4; off <<= 1) {
                int t = __shfl_up(wv, off, 64);
                if (lane >= off) wv += t;
            }
            wsum[lane] = wv;
        }
        __syncthreads();
        int waveoff = (wid == 0) ? 0 : wsum[wid - 1];
        int excl = carry + waveoff + incl - v;
        if (i < rsize) pexcl[i] = excl;
        __syncthreads();
        if (tid == 0) s_carry = carry + wsum[3];
        __syncthreads();
    }
    for (int i = tid; i < rsize; i += 256) {
        int pc = (lcnt[i] + 15) & ~15;
        rpbg[lo + i] = rbase + pexcl[i];
        rpeg[lo + i] = rbase + pexcl[i] + pc;
    }
    for (int i = tid; i < n; i += 256) {
        uint32_t p = bp[i];
        int slot = atomicAdd(&lcur[p >> 17], 1);
        sliceB[slot] = (int)p;
    }
    __syncthreads();
    for (int i = tid; i < n; i += 256) {
        uint32_t p = (uint32_t)sliceB[i];
        int r = p >> 17;
        og[pexcl[r] + (i - lexcl[r])] = (int)(p & 0x1FFFFu);
    }
    for (int r = tid; r < rsize; r += 256) {
        int c = lcnt[r], pc = (c + 15) & ~15, b = pexcl[r];
        for (int j = c; j < pc; ++j) og[b + j] = NNODE;
    }
}

// ---------------- mark nodes needed by the output gather ----------------
__global__ void mark_k(const int* __restrict__ sid, const int* __restrict__ eid,
                       int* __restrict__ flags) {
    int i = blockIdx.x * blockDim.x + threadIdx.x;
    if (i < BATCH) flags[sid[i]] = 1;
    else if (i < 2 * BATCH) flags[S_NUM + eid[i - BATCH]] = 1;
}

// ---------------- order-free compaction (atomic; output invariant to row order) -----------
__global__ void compact_k(const int* __restrict__ flags, int* __restrict__ list,
                          int* __restrict__ inv, int* __restrict__ nsel) {
    for (int i = blockIdx.x * blockDim.x + threadIdx.x; i < NNODE;
         i += gridDim.x * blockDim.x) {
        if (flags[i]) {
            int pos = atomicAdd(nsel, 1);
            list[pos] = i;
            inv[i] = pos;
        }
    }
}

// ---------------- cvt: featb(NT=8 tiled) = bf16([stu; exer]) + sentinels + padded cj -------
__global__ __launch_bounds__(256) void cvt1_k(const float* __restrict__ stu,
                                              const float* __restrict__ exer,
                                              const float* __restrict__ rcj,
                                              const float* __restrict__ wcj,
                                              uint4* __restrict__ featb,
                                              uint4* __restrict__ fcR,
                                              uint4* __restrict__ fcW,
                                              float* __restrict__ cjpR,
                                              float* __restrict__ cjpW) {
    const int main = NNODE * 16;           // uint4 per node (16)
    const int total = main + 48 + 2 * (NNODE + 1);
    const uint4 z4 = {0, 0, 0, 0};
    for (int i = blockIdx.x * blockDim.x + threadIdx.x; i < total;
         i += gridDim.x * blockDim.x) {
        if (i < main) {
            int node = i >> 4;
            int qq = i & 15;                // dims qq*8 .. qq*8+7
            const float4* src = (const float4*)((node < S_NUM)
                                  ? stu + (size_t)node * KDIM
                                  : exer + (size_t)(node - S_NUM) * KDIM);
            float4 a = src[qq * 2];
            float4 b = src[qq * 2 + 1];
            uint4 o;
            o.x = (uint32_t)f2bf(a.x) | ((uint32_t)f2bf(a.y) << 16);
            o.y = (uint32_t)f2bf(a.z) | ((uint32_t)f2bf(a.w) << 16);
            o.z = (uint32_t)f2bf(b.x) | ((uint32_t)f2bf(b.y) << 16);
            o.w = (uint32_t)f2bf(b.z) | ((uint32_t)f2bf(b.w) << 16);
            featb[(size_t)(qq >> 1) * PLANE_U4 + (size_t)node * 2 + (qq & 1)] = o;
        } else if (i < main + 48) {
            int j = i - main;
            int arr = j >> 4;               // 0..2
            int jj = j & 15;
            size_t off = (size_t)(jj >> 1) * PLANE_U4 + (size_t)NNODE * 2 + (jj & 1);
            if (arr == 0)      featb[off] = z4;
            else if (arr == 1) fcR[off] = z4;
            else               fcW[off] = z4;
        } else {
            int k = i - main - 48;
            if (k <= NNODE)  cjpR[k] = (k < NNODE) ? rcj[k] : 0.f;
            else {
                int m = k - (NNODE + 1);
                cjpW[m] = (m < NNODE) ? wcj[m] : 0.f;
            }
        }
    }
}

// ---------------- XCD-pinned persistent aggregation ----------------
// Block reads its REAL XCD id (HW_REG_XCC_ID) and claims node-chunks from that
// XCD's combo queues (tile = xcd; graph = pass). Gather plane = 2.24MB < 4MB L2
// -> L2-resident. Output written nontemporal to avoid evicting the plane.
// Drain phases cover all combos for correctness under any block->XCD placement.
template<int USECJ, int COMPACT>
__global__ __launch_bounds__(256) void aggp_k(const uint4* __restrict__ srcR,
                                              const uint4* __restrict__ srcW,
                                              const float* __restrict__ cjR,
                                              const float* __restrict__ cjW,
                                              const int* __restrict__ rpb,
                                              const int* __restrict__ rpe,
                                              const int* __restrict__ csr,
                                              const int* __restrict__ list,
                                              const int* __restrict__ nselp,
                                              int* __restrict__ qcur,
                                              uint4* __restrict__ outR,
                                              uint4* __restrict__ outW) {
    __shared__ int s_ch;
    uint32_t xcc;
    asm volatile("s_getreg_b32 %0, hwreg(HW_REG_XCC_ID)" : "=s"(xcc));
    xcc &= 7;
    const int nwork = COMPACT ? nselp[0] : NNODE;
    const int nchunks = (nwork + CH - 1) / CH;
    const int nslot = threadIdx.x >> 1;    // 0..127 node slot
    const int l2 = threadIdx.x & 1;
    const int4* csr4 = (const int4*)csr;

    for (int phase = 0; phase < 18; ++phase) {
        int cidx = (phase < 2) ? (phase * 8 + (int)xcc) : (phase - 2);
        int tile = cidx & 7, graph = cidx >> 3;
        const uint4* fc = (graph ? srcW : srcR) + (size_t)tile * PLANE_U4;
        const float* cjg = graph ? cjW : cjR;
        const int* rpbg = rpb + graph * NNODE;
        const int* rpeg = rpe + graph * NNODE;
        uint4* outp = (graph ? outW : outR) + (size_t)tile * PLANE_U4;
        for (;;) {
            if (threadIdx.x == 0) s_ch = atomicAdd(&qcur[cidx], 1);
            __syncthreads();
            int ch = s_ch;
            __syncthreads();
            if (ch >= nchunks) break;
            int ci = ch * CH + nslot;
            if (ci < nwork) {
                int n = COMPACT ? list[ci] : ci;
                int beg = rpbg[n], end = rpeg[n];
                f32x2 a0 = {0.f, 0.f}, a1 = {0.f, 0.f}, a2 = {0.f, 0.f}, a3 = {0.f, 0.f};
                for (int e = beg; e < end; e += 8) {
                    int4 sa = csr4[e >> 2];
                    int4 sb = csr4[(e >> 2) + 1];
                    uint4 u0 = fc[(size_t)sa.x * 2 + l2];
                    uint4 u1 = fc[(size_t)sa.y * 2 + l2];
                    uint4 u2 = fc[(size_t)sa.z * 2 + l2];
                    uint4 u3 = fc[(size_t)sa.w * 2 + l2];
                    uint4 u4 = fc[(size_t)sb.x * 2 + l2];
                    uint4 u5 = fc[(size_t)sb.y * 2 + l2];
                    uint4 u6 = fc[(size_t)sb.z * 2 + l2];
                    uint4 u7 = fc[(size_t)sb.w * 2 + l2];
                    if (USECJ) {
                        float c0 = cjg[sa.x], c1 = cjg[sa.y], c2 = cjg[sa.z], c3 = cjg[sa.w];
                        float c4 = cjg[sb.x], c5 = cjg[sb.y], c6 = cjg[sb.z], c7 = cjg[sb.w];
                        f32x2 v0 = {c0, c0}, v1 = {c1, c1}, v2 = {c2, c2}, v3 = {c3, c3};
                        f32x2 v4 = {c4, c4}, v5 = {c5, c5}, v6 = {c6, c6}, v7 = {c7, c7};
                        a0 += v0 * up2(u0.x) + v1 * up2(u1.x) + v2 * up2(u2.x) + v3 * up2(u3.x)
                            + v4 * up2(u4.x) + v5 * up2(u5.x) + v6 * up2(u6.x) + v7 * up2(u7.x);
                        a1 += v0 * up2(u0.y) + v1 * up2(u1.y) + v2 * up2(u2.y) + v3 * up2(u3.y)
                            + v4 * up2(u4.y) + v5 * up2(u5.y) + v6 * up2(u6.y) + v7 * up2(u7.y);
                        a2 += v0 * up2(u0.z) + v1 * up2(u1.z) + v2 * up2(u2.z) + v3 * up2(u3.z)
                            + v4 * up2(u4.z) + v5 * up2(u5.z) + v6 * up2(u6.z) + v7 * up2(u7.z);
                        a3 += v0 * up2(u0.w) + v1 * up2(u1.w) + v2 * up2(u2.w) + v3 * up2(u3.w)
                            + v4 * up2(u4.w) + v5 * up2(u5.w) + v6 * up2(u6.w) + v7 * up2(u7.w);
                    } else {
                        a0 += (up2(u0.x) + up2(u1.x)) + (up2(u2.x) + up2(u3.x))
                            + (up2(u4.x) + up2(u5.x)) + (up2(u6.x) + up2(u7.x));
                        a1 += (up2(u0.y) + up2(u1.y)) + (up2(u2.y) + up2(u3.y))
                            + (up2(u4.y) + up2(u5.y)) + (up2(u6.y) + up2(u7.y));
                        a2 += (up2(u0.z) + up2(u1.z)) + (up2(u2.z) + up2(u3.z))
                            + (up2(u4.z) + up2(u5.z)) + (up2(u6.z) + up2(u7.z));
                        a3 += (up2(u0.w) + up2(u1.w)) + (up2(u2.w) + up2(u3.w))
                            + (up2(u4.w) + up2(u5.w)) + (up2(u6.w) + up2(u7.w));
                    }
                }
                u32x4 o;
                o.x = pk2(a0); o.y = pk2(a1); o.z = pk2(a2); o.w = pk2(a3);
                __builtin_nontemporal_store(o, (u32x4*)&outp[(size_t)ci * 2 + l2]);
            }
        }
    }
}

// ---------------- fused GEMM, both graphs, 256 rows/block; NT=8 tiled A --------------------
template<int COMPACT>
__global__ __launch_bounds__(256) void gemm2_k(const ushort* __restrict__ AR,
                                               const ushort* __restrict__ AW,
                                               const ushort* __restrict__ wsR,
                                               const ushort* __restrict__ wsW,
                                               const float* __restrict__ rci,
                                               const float* __restrict__ rcj,
                                               const float* __restrict__ wci,
                                               const float* __restrict__ wcj,
                                               const int* __restrict__ list,
                                               const int* __restrict__ nselp,
                                               ushort* __restrict__ outR,
                                               ushort* __restrict__ outW,
                                               int mode) {
    const int halfBlocks = COMPACT ? (CAPC / GR) : ((NNODE + GR - 1) / GR);
    int graph = blockIdx.x >= halfBlocks;
    int bb = graph ? blockIdx.x - halfBlocks : blockIdx.x;
    int nrows = COMPACT ? nselp[0] : NNODE;
    const ushort* A = graph ? AW : AR;
    const ushort* wsm = graph ? wsW : wsR;
    const float* ci = graph ? wci : rci;
    const float* cj = graph ? wcj : rcj;
    ushort* outB = graph ? outW : outR;

    __shared__ ushort wt[32768];   // 64 KB: hi + lo plane, pre-swizzled
    {
        const uint4* g = (const uint4*)wsm;
        uint4* l = (uint4*)wt;
        for (int i = threadIdx.x; i < 4096; i += 256) l[i] = g[i];
    }
    __syncthreads();

    int wid = threadIdx.x >> 6, lane = threadIdx.x & 63;
    int q = lane >> 4, l16 = lane & 15;
    int rbase = bb * GR + wid * 64;
    if (rbase >= nrows) return;

    short8 z8 = {0, 0, 0, 0, 0, 0, 0, 0};
    short8 afr[4][4];
    #pragma unroll
    for (int t = 0; t < 4; ++t) {
        int row = rbase + t * 16 + l16;
        bool rok = row < nrows;
        #pragma unroll
        for (int kb = 0; kb < 4; ++kb) {
            int plane = kb * 2 + (q >> 1);
            afr[t][kb] = rok ? *(const short8*)(A + (size_t)plane * PLANE_E
                                                + (size_t)row * TDIM + (q & 1) * 8)
                             : z8;
        }
    }
    float scal[4][4];
    #pragma unroll
    for (int t = 0; t < 4; ++t)
        #pragma unroll
        for (int b = 0; b < 4; ++b) {
            int r = rbase + t * 16 + q * 4 + b;
            bool ok = r < nrows;
            int node = COMPACT ? (ok ? list[r] : 0) : r;
            scal[t][b] = ok ? (mode ? ci[node] * cj[node] : ci[node]) : 0.f;
        }

    #pragma unroll
    for (int cb = 0; cb < 8; ++cb) {
        int c = cb * 16 + l16;
        short8 bHi[4], bLo[4];
        #pragma unroll
        for (int kb = 0; kb < 4; ++kb) {
            int byte = (c * 256 + 2 * (kb * 32 + q * 8)) ^ ((c & 7) << 4);
            bHi[kb] = *(const short8*)((const char*)wt + byte);
            bLo[kb] = *(const short8*)((const char*)wt + 32768 + byte);
        }
        #pragma unroll
        for (int t = 0; t < 4; ++t) {
            f32x4 acc = {0.f, 0.f, 0.f, 0.f};
            #pragma unroll
            for (int kb = 0; kb < 4; ++kb) {
                acc = __builtin_amdgcn_mfma_f32_16x16x32_bf16(afr[t][kb], bHi[kb], acc, 0, 0, 0);
                acc = __builtin_amdgcn_mfma_f32_16x16x32_bf16(afr[t][kb], bLo[kb], acc, 0, 0, 0);
            }
            #pragma unroll
            for (int b = 0; b < 4; ++b) {
                int r = rbase + t * 16 + q * 4 + b;
                if (r < nrows) {
                    ushort v = f2bf(acc[b] * scal[t][b]);
                    if (COMPACT) outB[(size_t)r * KDIM + c] = v;
                    else outB[(size_t)cb * PLANE_E + (size_t)r * TDIM + l16] = v;
                }
            }
        }
    }
}

// ---------------- output assembly (compacted w1c/w2c bf16 -> f32 out) ----------------
__global__ void out_k(const ushort* __restrict__ w1c, const ushort* __restrict__ w2c,
                      const int* __restrict__ inv,
                      const float* __restrict__ disc, const float* __restrict__ kn,
                      const int* __restrict__ sid, const int* __restrict__ eid,
                      float* __restrict__ out) {
    const int total = 2 * BATCH * KDIM + BATCH + KDIM * KDIM;
    for (int i = blockIdx.x * blockDim.x + threadIdx.x; i < total;
         i += gridDim.x * blockDim.x) {
        if (i < BATCH * KDIM) {
            int b = i >> 7, c = i & 127;
            size_t r = (size_t)inv[sid[b]];
            out[i] = bf2f(w1c[r * KDIM + c]) + bf2f(w2c[r * KDIM + c]);
        } else if (i < 2 * BATCH * KDIM) {
            int j = i - BATCH * KDIM;
            int b = j >> 7, c = j & 127;
            size_t r = (size_t)inv[S_NUM + eid[b]];
            out[i] = bf2f(w1c[r * KDIM + c]) + bf2f(w2c[r * KDIM + c]);
        } else if (i < 2 * BATCH * KDIM + BATCH) {
            out[i] = disc[eid[i - 2 * BATCH * KDIM]];
        } else {
            out[i] = kn[i - (2 * BATCH * KDIM + BATCH)];
        }
    }
}

static inline size_t align_up(size_t x) { return (x + 255) & ~(size_t)255; }

extern "C" void kernel_launch(void* const* d_in, const int* in_sizes, int n_in,
                              void* d_out, int out_size, void* d_ws, size_t ws_size,
                              hipStream_t stream) {
    const float* stu  = (const float*)d_in[0];
    const float* exer = (const float*)d_in[1];
    const float* kn   = (const float*)d_in[2];
    const float* disc = (const float*)d_in[3];
    const float* rW   = (const float*)d_in[4];
    const float* wW   = (const float*)d_in[5];
    const float* rci  = (const float*)d_in[6];
    const float* rcj  = (const float*)d_in[7];
    const float* wci  = (const float*)d_in[8];
    const float* wcj  = (const float*)d_in[9];
    const int* redge   = (const int*)d_in[10];
    const int* wedge   = (const int*)d_in[11];
    const int* sid     = (const int*)d_in[12];
    const int* eid     = (const int*)d_in[13];
    float* out         = (float*)d_out;

    char* p = (char*)d_ws;
    const size_t fB16 = align_up((size_t)NT * PLANE_E * 2);   // 17.92 MB tiled
    ushort* featb = (ushort*)p; p += fB16;  // L1 gather src (tiled); later w1c/w2c
    ushort* fcR = (ushort*)p; p += fB16;    // tiled
    ushort* fcW = (ushort*)p; p += fB16;    // tiled
    ushort* pR  = (ushort*)p; p += fB16;    // tiled agg out; aliases buckets pre-L1
    ushort* pW  = (ushort*)p; p += fB16;
    ushort* ws  = (ushort*)p; p += align_up((size_t)6 * 32768 * 2);   // 384 KB
    int* gbcnt = (int*)p; p += align_up((size_t)256 * 4);
    int* rpb = (int*)p; p += align_up((size_t)2 * NNODE * 4);
    int* rpe = (int*)p; p += align_up((size_t)2 * NNODE * 4);
    int* csr = (int*)p; p += align_up((size_t)256 * RCAP * 4);
    float* cjpR = (float*)p; p += align_up((size_t)(NNODE + 1) * 4);
    float* cjpW = (float*)p; p += align_up((size_t)(NNODE + 1) * 4);
    int* flags = (int*)p; p += align_up((size_t)NNODE * 4);
    int* list  = (int*)p; p += align_up((size_t)CAPC * 4);
    int* inv   = (int*)p; p += align_up((size_t)NNODE * 4);
    int* nsel  = (int*)p; p += align_up((size_t)16 * 4);
    int* qcur  = (int*)p; p += align_up((size_t)48 * 4);      // 3 layers x 16 combos
    // buckets alias pR (256 x 8448 x 4B = 8.65 MB < 17.92 MB)
    uint32_t* bpk = (uint32_t*)pR;
    // compact outputs alias featb (2 x 16384 x 128 x 2B = 8 MB < 17.92 MB)
    ushort* w1c = featb;
    ushort* w2c = featb + (size_t)CAPC * KDIM;

    const int aggGrid = 2048;                       // persistent: 256 CU x 8 blocks
    const int gemmFull = 2 * ((NNODE + GR - 1) / GR);
    const int gemmComp = 2 * (CAPC / GR);
    const int NB = (NEDGE + CHUNK - 1) / CHUNK;

    // ---- shared prep ----
    prepW_k<<<(6 * 16384 + 255) / 256, 256, 0, stream>>>(rW, wW, ws, gbcnt, flags, nsel, qcur);
    bucket_k<<<2 * NB, 256, 0, stream>>>(redge, wedge, gbcnt, bpk);
    build_k<<<256, 256, 0, stream>>>(bpk, gbcnt, rpb, rpe, csr);
    mark_k<<<(2 * BATCH + 255) / 256, 256, 0, stream>>>(sid, eid, flags);
    compact_k<<<(NNODE + 255) / 256, 256, 0, stream>>>(flags, list, inv, nsel);
    cvt1_k<<<2048, 256, 0, stream>>>(stu, exer, rcj, wcj, (uint4*)featb,
                                     (uint4*)fcR, (uint4*)fcW, cjpR, cjpW);

    // ---- L1 (full; shared featb source) ----
    aggp_k<1, 0><<<aggGrid, 256, 0, stream>>>((const uint4*)featb, (const uint4*)featb,
                                              cjpR, cjpW, rpb, rpe, csr, nullptr, nullptr,
                                              qcur + 0, (uint4*)pR, (uint4*)pW);
    gemm2_k<0><<<gemmFull, 256, 0, stream>>>(pR, pW, ws + 0 * 32768, ws + 3 * 32768,
                                             rci, rcj, wci, wcj, nullptr, nullptr,
                                             fcR, fcW, 1);
    // ---- L2 (full) ----
    aggp_k<0, 0><<<aggGrid, 256, 0, stream>>>((const uint4*)fcR, (const uint4*)fcW,
                                              nullptr, nullptr, rpb, rpe, csr,
                                              nullptr, nullptr, qcur + 16,
                                              (uint4*)pR, (uint4*)pW);
    gemm2_k<0><<<gemmFull, 256, 0, stream>>>(pR, pW, ws + 1 * 32768, ws + 4 * 32768,
                                             rci, rcj, wci, wcj, nullptr, nullptr,
                                             fcR, fcW, 1);
    // ---- L3 (compact: only nodes the output reads) ----
    aggp_k<0, 1><<<aggGrid, 256, 0, stream>>>((const uint4*)fcR, (const uint4*)fcW,
                                              nullptr, nullptr, rpb, rpe, csr,
                                              list, nsel, qcur + 32,
                                              (uint4*)pR, (uint4*)pW);
    gemm2_k<1><<<gemmComp, 256, 0, stream>>>(pR, pW, ws + 2 * 32768, ws + 5 * 32768,
                                             rci, rcj, wci, wcj, list, nsel,
                                             w1c, w2c, 0);

    out_k<<<2048, 256, 0, stream>>>(w1c, w2c, inv, disc, kn, sid, eid, out);
}

// Round 15
// 375.064 us; speedup vs baseline: 4.6825x; 4.6825x over previous
//
#include <hip/hip_runtime.h>
#include <hip/hip_bf16.h>
#include <stdint.h>

#define S_NUM 50000
#define E_NUM 20000
#define NNODE 70000
#define KDIM 128
#define BATCH 8192
#define NEDGE 1000000

#define NRANGE 128            // dst-ranges per graph
#define RSZ 547               // ceil(NNODE / NRANGE)
#define BUCKET_CAP 8448       // per-bucket capacity (mean 7813, sigma 88)
#define RCAP 16672            // per-range padded csr region, mult of 16
#define CHUNK 8192            // edges per bucket_k block
#define BINCAP 120            // LDS bin capacity
#define GR 256                // gemm rows per block
#define CAPC 16384            // max compacted L3 nodes (2*BATCH)

typedef __attribute__((ext_vector_type(8))) short short8;
typedef __attribute__((ext_vector_type(4))) float f32x4;
typedef __attribute__((ext_vector_type(2))) float f32x2;

__device__ __forceinline__ float bf2f(ushort u) {
    union { uint32_t i; float f; } v; v.i = ((uint32_t)u) << 16; return v.f;
}
__device__ __forceinline__ ushort f2bf(float f) {
    union { uint32_t i; float f; } v; v.f = f;
    uint32_t r = v.i + 0x7fffu + ((v.i >> 16) & 1u);
    return (ushort)(r >> 16);
}
__device__ __forceinline__ f32x2 up2(uint32_t u) {
    union { uint32_t i; float f; } lo, hi;
    lo.i = u << 16; hi.i = u & 0xffff0000u;
    f32x2 r; r.x = lo.f; r.y = hi.f; return r;
}
__device__ __forceinline__ uint32_t pk2(f32x2 a) {
    return (uint32_t)f2bf(a.x) | ((uint32_t)f2bf(a.y) << 16);
}

// ---------------- prep0: T_g = W1_g @ W2_g (f32) + zero flags/gbcnt/nsel ----------------
__global__ __launch_bounds__(256) void prep0_k(const float* __restrict__ rW,
                                               const float* __restrict__ wW,
                                               float* __restrict__ Tprod,
                                               int* __restrict__ gbcnt,
                                               int* __restrict__ flags,
                                               int* __restrict__ nsel) {
    int b = blockIdx.x;
    if (b < 8) {
        int g = b >> 2, cq = b & 3;
        const float* W1 = g ? wW : rW;
        const float* W2 = (g ? wW : rW) + 16384;
        __shared__ float w2q[128][32];
        for (int i = threadIdx.x; i < 4096; i += 256)
            w2q[i >> 5][i & 31] = W2[(i >> 5) * 128 + cq * 32 + (i & 31)];
        __syncthreads();
        for (int o = threadIdx.x; o < 4096; o += 256) {
            int r = o >> 5, c = o & 31;
            float acc = 0.f;
            #pragma unroll 4
            for (int k = 0; k < 128; ++k)
                acc = fmaf(W1[r * 128 + k], w2q[k][c], acc);
            Tprod[(size_t)g * 16384 + r * 128 + cq * 32 + c] = acc;
        }
    } else {
        int t = (b - 8) * 256 + threadIdx.x;
        if (t < NNODE) flags[t] = 0;
        if (t < 256) gbcnt[t] = 0;
        if (t == 0) nsel[0] = 0;
    }
}

// ---------------- wprod2: Wf_g = T_g @ W3_g -> hi/lo bf16 split, swizzled into ws ----------
__global__ __launch_bounds__(256) void wprod2_k(const float* __restrict__ Tprod,
                                                const float* __restrict__ rW,
                                                const float* __restrict__ wW,
                                                ushort* __restrict__ ws) {
    int g = blockIdx.x >> 2, cq = blockIdx.x & 3;
    const float* T = Tprod + (size_t)g * 16384;
    const float* W3 = (g ? wW : rW) + 2 * 16384;
    __shared__ float w3q[128][32];
    for (int i = threadIdx.x; i < 4096; i += 256)
        w3q[i >> 5][i & 31] = W3[(i >> 5) * 128 + cq * 32 + (i & 31)];
    __syncthreads();
    ushort* wsg = ws + (size_t)g * 32768;
    for (int o = threadIdx.x; o < 4096; o += 256) {
        int r = o >> 5, cc = o & 31;
        int c = cq * 32 + cc;
        float acc = 0.f;
        #pragma unroll 4
        for (int k = 0; k < 128; ++k)
            acc = fmaf(T[r * 128 + k], w3q[k][cc], acc);
        ushort hb = f2bf(acc);
        ushort lb = f2bf(acc - bf2f(hb));
        int off = ((c * 256 + 2 * r) ^ ((c & 7) << 4)) >> 1;
        wsg[off] = hb;
        wsg[16384 + off] = lb;
    }
}

// ---------------- pass 1: bin edges by dst-range, packed (local_dst<<17 | src) -------------
__global__ __launch_bounds__(256) void bucket_k(const int* __restrict__ redge,
                                                const int* __restrict__ wedge,
                                                int* __restrict__ gbcnt,
                                                uint32_t* __restrict__ bpk) {
    __shared__ uint32_t lpk[NRANGE][BINCAP];
    __shared__ int lcnt[NRANGE];
    __shared__ int gbase[NRANGE];
    const int NB = (NEDGE + CHUNK - 1) / CHUNK;
    int bid = blockIdx.x;
    int graph = bid >= NB;
    int cb = graph ? bid - NB : bid;
    const int* eg = graph ? wedge : redge;
    int e0 = cb * CHUNK;
    int nthis = min(CHUNK, NEDGE - e0);
    for (int i = threadIdx.x; i < NRANGE; i += 256) lcnt[i] = 0;
    __syncthreads();
    for (int i = threadIdx.x; i < nthis; i += 256) {
        int s = eg[e0 + i];
        int d = eg[NEDGE + e0 + i];
        int b = d / RSZ;
        uint32_t p = ((uint32_t)(d - b * RSZ) << 17) | (uint32_t)s;
        int slot = atomicAdd(&lcnt[b], 1);
        if (slot < BINCAP) lpk[b][slot] = p;
        else {
            int gs = atomicAdd(&gbcnt[graph * NRANGE + b], 1);
            if (gs < BUCKET_CAP)
                bpk[(size_t)(graph * NRANGE + b) * BUCKET_CAP + gs] = p;
        }
    }
    __syncthreads();
    for (int b = threadIdx.x; b < NRANGE; b += 256) {
        int c = min(lcnt[b], BINCAP);
        lcnt[b] = c;
        gbase[b] = atomicAdd(&gbcnt[graph * NRANGE + b], c);
    }
    __syncthreads();
    for (int b = 0; b < NRANGE; ++b) {
        int c = lcnt[b];
        size_t base = (size_t)(graph * NRANGE + b) * BUCKET_CAP + gbase[b];
        for (int i = threadIdx.x; i < c; i += 256)
            if (gbase[b] + i < BUCKET_CAP) bpk[base + i] = lpk[b][i];
    }
}

// ---------------- pass 2: CSR slice in LDS, 16-padded rows, fixed per-combo regions --------
__global__ __launch_bounds__(256) void build_k(const uint32_t* __restrict__ bpk,
                                               const int* __restrict__ gbcnt,
                                               int* __restrict__ rpb,
                                               int* __restrict__ rpe,
                                               int* __restrict__ csr) {
    __shared__ int lcnt[RSZ];
    __shared__ int lexcl[RSZ];
    __shared__ int pexcl[RSZ];
    __shared__ int lcur[RSZ];
    __shared__ int sliceB[BUCKET_CAP];
    __shared__ int wsum[4];
    __shared__ int s_carry;
    int combo = blockIdx.x;                 // 0..255
    int graph = combo >> 7, grp = combo & (NRANGE - 1);
    int lo = grp * RSZ;
    int rsize = min(RSZ, NNODE - lo);
    int n = min(gbcnt[combo], BUCKET_CAP);
    const uint32_t* bp = bpk + (size_t)combo * BUCKET_CAP;
    int* rpbg = rpb + graph * NNODE;
    int* rpeg = rpe + graph * NNODE;
    int* og = csr + (size_t)combo * RCAP;
    const int rbase = combo * RCAP;
    int tid = threadIdx.x, lane = tid & 63, wid = tid >> 6;

    for (int i = tid; i < rsize; i += 256) lcnt[i] = 0;
    if (tid == 0) s_carry = 0;
    __syncthreads();
    for (int i = tid; i < n; i += 256)
        atomicAdd(&lcnt[bp[i] >> 17], 1);
    __syncthreads();
    // scan 1: real counts -> lexcl
    for (int base = 0; base < rsize; base += 256) {
        int i = base + tid;
        int v = (i < rsize) ? lcnt[i] : 0;
        int incl = v;
        #pragma unroll
        for (int off = 1; off < 64; off <<= 1) {
            int t = __shfl_up(incl, off, 64);
            if (lane >= off) incl += t;
        }
        if (lane == 63) wsum[wid] = incl;
        __syncthreads();
        int carry = s_carry;
        if (wid == 0 && lane < 4) {
            int wv = wsum[lane];
            #pragma unroll
            for (int off = 1; off < 4; off <<= 1) {
                int t = __shfl_up(wv, off, 64);
                if (lane >= off) wv += t;
            }
            wsum[lane] = wv;
        }
        __syncthreads();
        int waveoff = (wid == 0) ? 0 : wsum[wid - 1];
        int excl = carry + waveoff + incl - v;
        if (i < rsize) { lexcl[i] = excl; lcur[i] = excl; }
        __syncthreads();
        if (tid == 0) s_carry = carry + wsum[3];
        __syncthreads();
    }
    if (tid == 0) s_carry = 0;
    __syncthreads();
    // scan 2: padded counts -> pexcl
    for (int base = 0; base < rsize; base += 256) {
        int i = base + tid;
        int v = (i < rsize) ? ((lcnt[i] + 15) & ~15) : 0;
        int incl = v;
        #pragma unroll
        for (int off = 1; off < 64; off <<= 1) {
            int t = __shfl_up(incl, off, 64);
            if (lane >= off) incl += t;
        }
        if (lane == 63) wsum[wid] = incl;
        __syncthreads();
        int carry = s_carry;
        if (wid == 0 && lane < 4) {
            int wv = wsum[lane];
            #pragma unroll
            for (int off = 1; off < 4; off <<= 1) {
                int t = __shfl_up(wv, off, 64);
                if (lane >= off) wv += t;
            }
            wsum[lane] = wv;
        }
        __syncthreads();
        int waveoff = (wid == 0) ? 0 : wsum[wid - 1];
        int excl = carry + waveoff + incl - v;
        if (i < rsize) pexcl[i] = excl;
        __syncthreads();
        if (tid == 0) s_carry = carry + wsum[3];
        __syncthreads();
    }
    for (int i = tid; i < rsize; i += 256) {
        int pc = (lcnt[i] + 15) & ~15;
        rpbg[lo + i] = rbase + pexcl[i];
        rpeg[lo + i] = rbase + pexcl[i] + pc;
    }
    for (int i = tid; i < n; i += 256) {
        uint32_t p = bp[i];
        int slot = atomicAdd(&lcur[p >> 17], 1);
        sliceB[slot] = (int)p;
    }
    __syncthreads();
    for (int i = tid; i < n; i += 256) {
        uint32_t p = (uint32_t)sliceB[i];
        int r = p >> 17;
        og[pexcl[r] + (i - lexcl[r])] = (int)(p & 0x1FFFFu);
    }
    for (int r = tid; r < rsize; r += 256) {
        int c = lcnt[r], pc = (c + 15) & ~15, b = pexcl[r];
        for (int j = c; j < pc; ++j) og[b + j] = NNODE;
    }
}

// ---------------- mark nodes needed by the output gather ----------------
__global__ void mark_k(const int* __restrict__ sid, const int* __restrict__ eid,
                       int* __restrict__ flags) {
    int i = blockIdx.x * blockDim.x + threadIdx.x;
    if (i < BATCH) flags[sid[i]] = 1;
    else if (i < 2 * BATCH) flags[S_NUM + eid[i - BATCH]] = 1;
}

// ---------------- order-free compaction (atomic; output invariant to row order) -----------
__global__ void compact_k(const int* __restrict__ flags, int* __restrict__ list,
                          int* __restrict__ inv, int* __restrict__ nsel) {
    for (int i = blockIdx.x * blockDim.x + threadIdx.x; i < NNODE;
         i += gridDim.x * blockDim.x) {
        if (flags[i]) {
            int pos = atomicAdd(nsel, 1);
            list[pos] = i;
            inv[i] = pos;
        }
    }
}

// ---------------- cvt: featb = bf16([stu; exer]) + sentinels + weight arrays ----------------
__global__ __launch_bounds__(256) void cvt_k(const float* __restrict__ stu,
                                             const float* __restrict__ exer,
                                             const float* __restrict__ rci,
                                             const float* __restrict__ rcj,
                                             const float* __restrict__ wci,
                                             const float* __restrict__ wcj,
                                             uint4* __restrict__ featb,
                                             uint4* __restrict__ pR,
                                             uint4* __restrict__ pW,
                                             uint4* __restrict__ qW,
                                             float* __restrict__ cjpR,
                                             float* __restrict__ cjpW,
                                             float* __restrict__ ccR,
                                             float* __restrict__ ccW) {
    const int main = NNODE * 16;           // uint4 per node
    const int total = main + 64 + (NNODE + 1);
    const uint4 z4 = {0, 0, 0, 0};
    for (int i = blockIdx.x * blockDim.x + threadIdx.x; i < total;
         i += gridDim.x * blockDim.x) {
        if (i < main) {
            int node = i >> 4;
            int qq = i & 15;
            const float4* src = (const float4*)((node < S_NUM)
                                  ? stu + (size_t)node * KDIM
                                  : exer + (size_t)(node - S_NUM) * KDIM);
            float4 a = src[qq * 2];
            float4 b = src[qq * 2 + 1];
            uint4 o;
            o.x = (uint32_t)f2bf(a.x) | ((uint32_t)f2bf(a.y) << 16);
            o.y = (uint32_t)f2bf(a.z) | ((uint32_t)f2bf(a.w) << 16);
            o.z = (uint32_t)f2bf(b.x) | ((uint32_t)f2bf(b.y) << 16);
            o.w = (uint32_t)f2bf(b.z) | ((uint32_t)f2bf(b.w) << 16);
            featb[i] = o;
        } else if (i < main + 64) {
            int j = i - main;
            size_t off = (size_t)NNODE * 16 + (j & 15);
            switch (j >> 4) {
                case 0: featb[off] = z4; break;
                case 1: pR[off] = z4; break;
                case 2: pW[off] = z4; break;
                default: qW[off] = z4; break;
            }
        } else {
            int k = i - main - 64;         // 0..NNODE
            bool in = k < NNODE;
            cjpR[k] = in ? rcj[k] : 0.f;
            cjpW[k] = in ? wcj[k] : 0.f;
            ccR[k] = in ? rci[k] * rcj[k] : 0.f;
            ccW[k] = in ? wci[k] * wcj[k] : 0.f;
        }
    }
}

// ---------------- weighted aggregation: 16-lane group = one node ----------------
// lane&15 owns 8 dims (uint4); no cross-lane reduction; rows padded to mult-16
// with sentinel src NNODE (zero row, weight 0). COMPACT: compacted node list.
template<int COMPACT>
__global__ __launch_bounds__(256) void agg_k(const uint4* __restrict__ srcR,
                                             const uint4* __restrict__ srcW,
                                             const float* __restrict__ wR,
                                             const float* __restrict__ wWt,
                                             const int* __restrict__ rpb,
                                             const int* __restrict__ rpe,
                                             const int* __restrict__ csr,
                                             const int* __restrict__ list,
                                             const int* __restrict__ nselp,
                                             uint4* __restrict__ outR,
                                             uint4* __restrict__ outW) {
    int lane = threadIdx.x & 63, wid = threadIdx.x >> 6;
    int grp = lane >> 4, c16 = lane & 15;
    int gi = blockIdx.x * 16 + wid * 4 + grp;
    int graph, n, orow;
    if (COMPACT) {
        int nsel = nselp[0];
        graph = gi >= CAPC;
        int ci = graph ? gi - CAPC : gi;
        if (ci >= nsel) return;
        n = list[ci];
        orow = ci;
    } else {
        if (gi >= 2 * NNODE) return;
        graph = gi >= NNODE;
        n = graph ? gi - NNODE : gi;
        orow = n;
    }
    const uint4* fc = graph ? srcW : srcR;
    const float* wg = graph ? wWt : wR;
    int beg = (rpb + graph * NNODE)[n];
    int end = (rpe + graph * NNODE)[n];
    uint4* outp = graph ? outW : outR;

    f32x2 a0 = {0.f, 0.f}, a1 = {0.f, 0.f}, a2 = {0.f, 0.f}, a3 = {0.f, 0.f};
    for (int e = beg; e < end; e += 8) {
        int s0 = csr[e],     s1 = csr[e + 1], s2 = csr[e + 2], s3 = csr[e + 3];
        int s4 = csr[e + 4], s5 = csr[e + 5], s6 = csr[e + 6], s7 = csr[e + 7];
        uint4 u0 = fc[(size_t)s0 * 16 + c16];
        uint4 u1 = fc[(size_t)s1 * 16 + c16];
        uint4 u2 = fc[(size_t)s2 * 16 + c16];
        uint4 u3 = fc[(size_t)s3 * 16 + c16];
        uint4 u4 = fc[(size_t)s4 * 16 + c16];
        uint4 u5 = fc[(size_t)s5 * 16 + c16];
        uint4 u6 = fc[(size_t)s6 * 16 + c16];
        uint4 u7 = fc[(size_t)s7 * 16 + c16];
        float c0 = wg[s0], c1 = wg[s1], c2 = wg[s2], c3 = wg[s3];
        float c4 = wg[s4], c5 = wg[s5], c6 = wg[s6], c7 = wg[s7];
        f32x2 v0 = {c0, c0}, v1 = {c1, c1}, v2 = {c2, c2}, v3 = {c3, c3};
        f32x2 v4 = {c4, c4}, v5 = {c5, c5}, v6 = {c6, c6}, v7 = {c7, c7};
        a0 += v0 * up2(u0.x) + v1 * up2(u1.x) + v2 * up2(u2.x) + v3 * up2(u3.x)
            + v4 * up2(u4.x) + v5 * up2(u5.x) + v6 * up2(u6.x) + v7 * up2(u7.x);
        a1 += v0 * up2(u0.y) + v1 * up2(u1.y) + v2 * up2(u2.y) + v3 * up2(u3.y)
            + v4 * up2(u4.y) + v5 * up2(u5.y) + v6 * up2(u6.y) + v7 * up2(u7.y);
        a2 += v0 * up2(u0.z) + v1 * up2(u1.z) + v2 * up2(u2.z) + v3 * up2(u3.z)
            + v4 * up2(u4.z) + v5 * up2(u5.z) + v6 * up2(u6.z) + v7 * up2(u7.z);
        a3 += v0 * up2(u0.w) + v1 * up2(u1.w) + v2 * up2(u2.w) + v3 * up2(u3.w)
            + v4 * up2(u4.w) + v5 * up2(u5.w) + v6 * up2(u6.w) + v7 * up2(u7.w);
    }
    uint4 o;
    o.x = pk2(a0); o.y = pk2(a1); o.z = pk2(a2); o.w = pk2(a3);
    outp[(size_t)orow * 16 + c16] = o;
}

// ---------------- compact GEMM: out = ci ⊙ (A @ Wf), A bf16, Wf pre-split hi/lo -----------
__global__ __launch_bounds__(256) void gemmc_k(const ushort* __restrict__ AR,
                                               const ushort* __restrict__ AW,
                                               const ushort* __restrict__ ws,
                                               const float* __restrict__ rci,
                                               const float* __restrict__ wci,
                                               const int* __restrict__ list,
                                               const int* __restrict__ nselp,
                                               ushort* __restrict__ w1c,
                                               ushort* __restrict__ w2c) {
    const int halfBlocks = CAPC / GR;
    int graph = blockIdx.x >= halfBlocks;
    int bb = graph ? blockIdx.x - halfBlocks : blockIdx.x;
    int nrows = nselp[0];
    const ushort* A = graph ? AW : AR;
    const ushort* wsm = ws + (size_t)graph * 32768;
    const float* ci = graph ? wci : rci;
    ushort* outB = graph ? w2c : w1c;

    __shared__ ushort wt[32768];   // 64 KB: hi + lo plane, pre-swizzled
    {
        const uint4* g = (const uint4*)wsm;
        uint4* l = (uint4*)wt;
        for (int i = threadIdx.x; i < 4096; i += 256) l[i] = g[i];
    }
    __syncthreads();

    int wid = threadIdx.x >> 6, lane = threadIdx.x & 63;
    int q = lane >> 4, l16 = lane & 15;
    int rbase = bb * GR + wid * 64;
    if (rbase >= nrows) return;

    short8 z8 = {0, 0, 0, 0, 0, 0, 0, 0};
    short8 afr[4][4];
    #pragma unroll
    for (int t = 0; t < 4; ++t) {
        int row = rbase + t * 16 + l16;
        bool rok = row < nrows;
        const short8* ar = (const short8*)(A + (size_t)row * KDIM);
        #pragma unroll
        for (int kb = 0; kb < 4; ++kb)
            afr[t][kb] = rok ? ar[kb * 4 + q] : z8;
    }
    float scal[4][4];
    #pragma unroll
    for (int t = 0; t < 4; ++t)
        #pragma unroll
        for (int b = 0; b < 4; ++b) {
            int r = rbase + t * 16 + q * 4 + b;
            bool ok = r < nrows;
            int node = ok ? list[r] : 0;
            scal[t][b] = ok ? ci[node] : 0.f;
        }

    #pragma unroll
    for (int cb = 0; cb < 8; ++cb) {
        int c = cb * 16 + l16;
        short8 bHi[4], bLo[4];
        #pragma unroll
        for (int kb = 0; kb < 4; ++kb) {
            int byte = (c * 256 + 2 * (kb * 32 + q * 8)) ^ ((c & 7) << 4);
            bHi[kb] = *(const short8*)((const char*)wt + byte);
            bLo[kb] = *(const short8*)((const char*)wt + 32768 + byte);
        }
        #pragma unroll
        for (int t = 0; t < 4; ++t) {
            f32x4 acc = {0.f, 0.f, 0.f, 0.f};
            #pragma unroll
            for (int kb = 0; kb < 4; ++kb) {
                acc = __builtin_amdgcn_mfma_f32_16x16x32_bf16(afr[t][kb], bHi[kb], acc, 0, 0, 0);
                acc = __builtin_amdgcn_mfma_f32_16x16x32_bf16(afr[t][kb], bLo[kb], acc, 0, 0, 0);
            }
            #pragma unroll
            for (int b = 0; b < 4; ++b) {
                int r = rbase + t * 16 + q * 4 + b;
                if (r < nrows)
                    outB[(size_t)r * KDIM + c] = f2bf(acc[b] * scal[t][b]);
            }
        }
    }
}

// ---------------- output assembly (compacted w1c/w2c bf16 -> f32 out) ----------------
__global__ void out_k(const ushort* __restrict__ w1c, const ushort* __restrict__ w2c,
                      const int* __restrict__ inv,
                      const float* __restrict__ disc, const float* __restrict__ kn,
                      const int* __restrict__ sid, const int* __restrict__ eid,
                      float* __restrict__ out) {
    const int total = 2 * BATCH * KDIM + BATCH + KDIM * KDIM;
    for (int i = blockIdx.x * blockDim.x + threadIdx.x; i < total;
         i += gridDim.x * blockDim.x) {
        if (i < BATCH * KDIM) {
            int b = i >> 7, c = i & 127;
            size_t r = (size_t)inv[sid[b]];
            out[i] = bf2f(w1c[r * KDIM + c]) + bf2f(w2c[r * KDIM + c]);
        } else if (i < 2 * BATCH * KDIM) {
            int j = i - BATCH * KDIM;
            int b = j >> 7, c = j & 127;
            size_t r = (size_t)inv[S_NUM + eid[b]];
            out[i] = bf2f(w1c[r * KDIM + c]) + bf2f(w2c[r * KDIM + c]);
        } else if (i < 2 * BATCH * KDIM + BATCH) {
            out[i] = disc[eid[i - 2 * BATCH * KDIM]];
        } else {
            out[i] = kn[i - (2 * BATCH * KDIM + BATCH)];
        }
    }
}

static inline size_t align_up(size_t x) { return (x + 255) & ~(size_t)255; }

extern "C" void kernel_launch(void* const* d_in, const int* in_sizes, int n_in,
                              void* d_out, int out_size, void* d_ws, size_t ws_size,
                              hipStream_t stream) {
    const float* stu  = (const float*)d_in[0];
    const float* exer = (const float*)d_in[1];
    const float* kn   = (const float*)d_in[2];
    const float* disc = (const float*)d_in[3];
    const float* rW   = (const float*)d_in[4];
    const float* wW   = (const float*)d_in[5];
    const float* rci  = (const float*)d_in[6];
    const float* rcj  = (const float*)d_in[7];
    const float* wci  = (const float*)d_in[8];
    const float* wcj  = (const float*)d_in[9];
    const int* redge   = (const int*)d_in[10];
    const int* wedge   = (const int*)d_in[11];
    const int* sid     = (const int*)d_in[12];
    const int* eid     = (const int*)d_in[13];
    float* out         = (float*)d_out;

    char* p = (char*)d_ws;
    const size_t fB16 = align_up((size_t)(NNODE + 1) * KDIM * 2);   // +sentinel row
    ushort* featb = (ushort*)p; p += fB16;  // L1 src; then qR (L2 out); then w1c/w2c
    ushort* pR  = (ushort*)p; p += fB16;    // L1 out / L2 src / L3 out; aliases buckets
    ushort* pW  = (ushort*)p; p += fB16;
    ushort* qW  = (ushort*)p; p += fB16;    // L2 out (graph W) / L3 src
    ushort* ws  = (ushort*)p; p += align_up((size_t)2 * 32768 * 2);   // 128 KB Wf
    float* Tprod = (float*)p; p += align_up((size_t)2 * 16384 * 4);   // 128 KB
    int* gbcnt = (int*)p; p += align_up((size_t)256 * 4);
    int* rpb = (int*)p; p += align_up((size_t)2 * NNODE * 4);
    int* rpe = (int*)p; p += align_up((size_t)2 * NNODE * 4);
    int* csr = (int*)p; p += align_up((size_t)256 * RCAP * 4);
    float* cjpR = (float*)p; p += align_up((size_t)(NNODE + 1) * 4);
    float* cjpW = (float*)p; p += align_up((size_t)(NNODE + 1) * 4);
    float* ccR  = (float*)p; p += align_up((size_t)(NNODE + 1) * 4);
    float* ccW  = (float*)p; p += align_up((size_t)(NNODE + 1) * 4);
    int* flags = (int*)p; p += align_up((size_t)NNODE * 4);
    int* list  = (int*)p; p += align_up((size_t)CAPC * 4);
    int* inv   = (int*)p; p += align_up((size_t)NNODE * 4);
    int* nsel  = (int*)p; p += align_up((size_t)16 * 4);
    // buckets alias pR (8.65 MB < 17.92 MB); consumed by build_k before agg1 writes pR
    uint32_t* bpk = (uint32_t*)pR;
    ushort* qR = featb;                       // L2 out aliases featb (dead after L1)
    ushort* w1c = featb;                      // final compact outputs alias featb/qR
    ushort* w2c = featb + (size_t)CAPC * KDIM;//   (dead after L3 agg reads qR)

    const int aggFull = (2 * NNODE + 15) / 16;      // 8750
    const int aggComp = 2 * CAPC / 16;              // 2048
    const int gemmComp = 2 * (CAPC / GR);           // 128
    const int NB = (NEDGE + CHUNK - 1) / CHUNK;

    // ---- prep: Wf = W1@W2@W3 (split+swizzled), CSR, compaction, cvt ----
    prep0_k<<<8 + (NNODE + 255) / 256, 256, 0, stream>>>(rW, wW, Tprod, gbcnt, flags, nsel);
    wprod2_k<<<8, 256, 0, stream>>>(Tprod, rW, wW, ws);
    bucket_k<<<2 * NB, 256, 0, stream>>>(redge, wedge, gbcnt, bpk);
    build_k<<<256, 256, 0, stream>>>(bpk, gbcnt, rpb, rpe, csr);
    mark_k<<<(2 * BATCH + 255) / 256, 256, 0, stream>>>(sid, eid, flags);
    compact_k<<<(NNODE + 255) / 256, 256, 0, stream>>>(flags, list, inv, nsel);
    cvt_k<<<2048, 256, 0, stream>>>(stu, exer, rci, rcj, wci, wcj, (uint4*)featb,
                                    (uint4*)pR, (uint4*)pW, (uint4*)qW,
                                    cjpR, cjpW, ccR, ccW);

    // ---- 3 weighted aggregations (GEMMs deferred into final Wf) ----
    agg_k<0><<<aggFull, 256, 0, stream>>>((const uint4*)featb, (const uint4*)featb,
                                          cjpR, cjpW, rpb, rpe, csr, nullptr, nullptr,
                                          (uint4*)pR, (uint4*)pW);
    agg_k<0><<<aggFull, 256, 0, stream>>>((const uint4*)pR, (const uint4*)pW,
                                          ccR, ccW, rpb, rpe, csr, nullptr, nullptr,
                                          (uint4*)qR, (uint4*)qW);
    agg_k<1><<<aggComp, 256, 0, stream>>>((const uint4*)qR, (const uint4*)qW,
                                          ccR, ccW, rpb, rpe, csr, list, nsel,
                                          (uint4*)pR, (uint4*)pW);
    // ---- single compact GEMM with Wf = W1@W2@W3, scale ci ----
    gemmc_k<<<gemmComp, 256, 0, stream>>>(pR, pW, ws, rci, wci, list, nsel, w1c, w2c);

    out_k<<<2048, 256, 0, stream>>>(w1c, w2c, inv, disc, kn, sid, eid, out);
}

// Round 16
// 334.628 us; speedup vs baseline: 5.2483x; 1.1208x over previous
//
#include <hip/hip_runtime.h>
#include <hip/hip_bf16.h>
#include <stdint.h>

#define S_NUM 50000
#define E_NUM 20000
#define NNODE 70000
#define KDIM 128
#define BATCH 8192
#define NEDGE 1000000

#define NRANGE 128            // dst-ranges per graph
#define RSZ 547               // ceil(NNODE / NRANGE)
#define BUCKET_CAP 8448       // per-bucket capacity (mean 7813, sigma 88)
#define RCAP 16672            // per-range padded csr region, mult of 16
#define CHUNK 8192            // edges per bucket_k block
#define BINCAP 120            // LDS bin capacity
#define GR 256                // gemm rows per block
#define CAPC 16384            // max compacted L3 nodes (2*BATCH)

typedef __attribute__((ext_vector_type(8))) short short8;
typedef __attribute__((ext_vector_type(4))) float f32x4;
typedef __attribute__((ext_vector_type(2))) float f32x2;

__device__ __forceinline__ float bf2f(ushort u) {
    union { uint32_t i; float f; } v; v.i = ((uint32_t)u) << 16; return v.f;
}
__device__ __forceinline__ ushort f2bf(float f) {
    union { uint32_t i; float f; } v; v.f = f;
    uint32_t r = v.i + 0x7fffu + ((v.i >> 16) & 1u);
    return (ushort)(r >> 16);
}
// unpack 2 bf16 (packed in uint32) -> f32x2 {lo, hi}
__device__ __forceinline__ f32x2 up2(uint32_t u) {
    union { uint32_t i; float f; } lo, hi;
    lo.i = u << 16; hi.i = u & 0xffff0000u;
    f32x2 r; r.x = lo.f; r.y = hi.f; return r;
}
__device__ __forceinline__ uint32_t pk2(f32x2 a) {
    return (uint32_t)f2bf(a.x) | ((uint32_t)f2bf(a.y) << 16);
}

// ---------------- W prep (+ gbcnt/flags/nsel zero): bf16 hi/lo split, swizzled ------------
__global__ void prepW_k(const float* __restrict__ rW, const float* __restrict__ wW,
                        ushort* __restrict__ ws, int* __restrict__ gbcnt,
                        int* __restrict__ flags, int* __restrict__ nsel) {
    int t = blockIdx.x * blockDim.x + threadIdx.x;
    if (blockIdx.x == 0 && threadIdx.x < 256) gbcnt[threadIdx.x] = 0;
    if (t == 0) nsel[0] = 0;
    if (t < NNODE) flags[t] = 0;
    if (t >= 6 * 16384) return;
    int m = t >> 14, idx = t & 16383;
    const float* W = (m < 3) ? rW + m * 16384 : wW + (m - 3) * 16384;
    float x = W[idx];
    int k = idx >> 7, c = idx & 127;
    ushort hb = f2bf(x);
    ushort lb = f2bf(x - bf2f(hb));
    int off = ((c * 256 + 2 * k) ^ ((c & 7) << 4)) >> 1;
    ws[(size_t)m * 32768 + off] = hb;
    ws[(size_t)m * 32768 + 16384 + off] = lb;
}

// ---------------- pass 1: bin edges by dst-range, packed (local_dst<<17 | src) -------------
__global__ __launch_bounds__(256) void bucket_k(const int* __restrict__ redge,
                                                const int* __restrict__ wedge,
                                                int* __restrict__ gbcnt,
                                                uint32_t* __restrict__ bpk) {
    __shared__ uint32_t lpk[NRANGE][BINCAP];
    __shared__ int lcnt[NRANGE];
    __shared__ int gbase[NRANGE];
    const int NB = (NEDGE + CHUNK - 1) / CHUNK;
    int bid = blockIdx.x;
    int graph = bid >= NB;
    int cb = graph ? bid - NB : bid;
    const int* eg = graph ? wedge : redge;
    int e0 = cb * CHUNK;
    int nthis = min(CHUNK, NEDGE - e0);
    for (int i = threadIdx.x; i < NRANGE; i += 256) lcnt[i] = 0;
    __syncthreads();
    for (int i = threadIdx.x; i < nthis; i += 256) {
        int s = eg[e0 + i];
        int d = eg[NEDGE + e0 + i];
        int b = d / RSZ;
        uint32_t p = ((uint32_t)(d - b * RSZ) << 17) | (uint32_t)s;
        int slot = atomicAdd(&lcnt[b], 1);
        if (slot < BINCAP) lpk[b][slot] = p;
        else {
            int gs = atomicAdd(&gbcnt[graph * NRANGE + b], 1);
            if (gs < BUCKET_CAP)
                bpk[(size_t)(graph * NRANGE + b) * BUCKET_CAP + gs] = p;
        }
    }
    __syncthreads();
    for (int b = threadIdx.x; b < NRANGE; b += 256) {
        int c = min(lcnt[b], BINCAP);
        lcnt[b] = c;
        gbase[b] = atomicAdd(&gbcnt[graph * NRANGE + b], c);
    }
    __syncthreads();
    for (int b = 0; b < NRANGE; ++b) {
        int c = lcnt[b];
        size_t base = (size_t)(graph * NRANGE + b) * BUCKET_CAP + gbase[b];
        for (int i = threadIdx.x; i < c; i += 256)
            if (gbase[b] + i < BUCKET_CAP) bpk[base + i] = lpk[b][i];
    }
}

// ---------------- pass 2: CSR slice in LDS, 16-padded rows, fixed per-combo regions --------
__global__ __launch_bounds__(256) void build_k(const uint32_t* __restrict__ bpk,
                                               const int* __restrict__ gbcnt,
                                               int* __restrict__ rpb,
                                               int* __restrict__ rpe,
                                               int* __restrict__ csr) {
    __shared__ int lcnt[RSZ];
    __shared__ int lexcl[RSZ];
    __shared__ int pexcl[RSZ];
    __shared__ int lcur[RSZ];
    __shared__ int sliceB[BUCKET_CAP];
    __shared__ int wsum[4];
    __shared__ int s_carry;
    int combo = blockIdx.x;                 // 0..255
    int graph = combo >> 7, grp = combo & (NRANGE - 1);
    int lo = grp * RSZ;
    int rsize = min(RSZ, NNODE - lo);
    int n = min(gbcnt[combo], BUCKET_CAP);
    const uint32_t* bp = bpk + (size_t)combo * BUCKET_CAP;
    int* rpbg = rpb + graph * NNODE;
    int* rpeg = rpe + graph * NNODE;
    int* og = csr + (size_t)combo * RCAP;
    const int rbase = combo * RCAP;
    int tid = threadIdx.x, lane = tid & 63, wid = tid >> 6;

    for (int i = tid; i < rsize; i += 256) lcnt[i] = 0;
    if (tid == 0) s_carry = 0;
    __syncthreads();
    for (int i = tid; i < n; i += 256)
        atomicAdd(&lcnt[bp[i] >> 17], 1);
    __syncthreads();
    // scan 1: real counts -> lexcl
    for (int base = 0; base < rsize; base += 256) {
        int i = base + tid;
        int v = (i < rsize) ? lcnt[i] : 0;
        int incl = v;
        #pragma unroll
        for (int off = 1; off < 64; off <<= 1) {
            int t = __shfl_up(incl, off, 64);
            if (lane >= off) incl += t;
        }
        if (lane == 63) wsum[wid] = incl;
        __syncthreads();
        int carry = s_carry;
        if (wid == 0 && lane < 4) {
            int wv = wsum[lane];
            #pragma unroll
            for (int off = 1; off < 4; off <<= 1) {
                int t = __shfl_up(wv, off, 64);
                if (lane >= off) wv += t;
            }
            wsum[lane] = wv;
        }
        __syncthreads();
        int waveoff = (wid == 0) ? 0 : wsum[wid - 1];
        int excl = carry + waveoff + incl - v;
        if (i < rsize) { lexcl[i] = excl; lcur[i] = excl; }
        __syncthreads();
        if (tid == 0) s_carry = carry + wsum[3];
        __syncthreads();
    }
    if (tid == 0) s_carry = 0;
    __syncthreads();
    // scan 2: padded counts -> pexcl
    for (int base = 0; base < rsize; base += 256) {
        int i = base + tid;
        int v = (i < rsize) ? ((lcnt[i] + 15) & ~15) : 0;
        int incl = v;
        #pragma unroll
        for (int off = 1; off < 64; off <<= 1) {
            int t = __shfl_up(incl, off, 64);
            if (lane >= off) incl += t;
        }
        if (lane == 63) wsum[wid] = incl;
        __syncthreads();
        int carry = s_carry;
        if (wid == 0 && lane < 4) {
            int wv = wsum[lane];
            #pragma unroll
            for (int off = 1; off < 4; off <<= 1) {
                int t = __shfl_up(wv, off, 64);
                if (lane >= off) wv += t;
            }
            wsum[lane] = wv;
        }
        __syncthreads();
        int waveoff = (wid == 0) ? 0 : wsum[wid - 1];
        int excl = carry + waveoff + incl - v;
        if (i < rsize) pexcl[i] = excl;
        __syncthreads();
        if (tid == 0) s_carry = carry + wsum[3];
        __syncthreads();
    }
    for (int i = tid; i < rsize; i += 256) {
        int pc = (lcnt[i] + 15) & ~15;
        rpbg[lo + i] = rbase + pexcl[i];
        rpeg[lo + i] = rbase + pexcl[i] + pc;
    }
    for (int i = tid; i < n; i += 256) {
        uint32_t p = bp[i];
        int slot = atomicAdd(&lcur[p >> 17], 1);
        sliceB[slot] = (int)p;
    }
    __syncthreads();
    for (int i = tid; i < n; i += 256) {
        uint32_t p = (uint32_t)sliceB[i];
        int r = p >> 17;
        og[pexcl[r] + (i - lexcl[r])] = (int)(p & 0x1FFFFu);
    }
    for (int r = tid; r < rsize; r += 256) {
        int c = lcnt[r], pc = (c + 15) & ~15, b = pexcl[r];
        for (int j = c; j < pc; ++j) og[b + j] = NNODE;
    }
}

// ---------------- fused mark+compact (first-setter wins; output order-invariant) -----------
__global__ void markcompact_k(const int* __restrict__ sid, const int* __restrict__ eid,
                              int* __restrict__ flags, int* __restrict__ list,
                              int* __restrict__ inv, int* __restrict__ nsel) {
    int i = blockIdx.x * blockDim.x + threadIdx.x;
    int node = -1;
    if (i < BATCH) node = sid[i];
    else if (i < 2 * BATCH) node = S_NUM + eid[i - BATCH];
    if (node >= 0 && atomicExch(&flags[node], 1) == 0) {
        int pos = atomicAdd(nsel, 1);
        list[pos] = node;
        inv[node] = pos;
    }
}

// ---------------- cvt: featb = bf16([stu; exer]) + sentinel rows + padded cj copies --------
__global__ __launch_bounds__(256) void cvt1_k(const float* __restrict__ stu,
                                              const float* __restrict__ exer,
                                              const float* __restrict__ rcj,
                                              const float* __restrict__ wcj,
                                              uint4* __restrict__ featb,
                                              uint4* __restrict__ fcR,
                                              uint4* __restrict__ fcW,
                                              float* __restrict__ cjpR,
                                              float* __restrict__ cjpW) {
    const int main = NNODE * 16;           // uint4 per row
    const int total = main + 48 + 2 * (NNODE + 1);
    const uint4 z4 = {0, 0, 0, 0};
    for (int i = blockIdx.x * blockDim.x + threadIdx.x; i < total;
         i += gridDim.x * blockDim.x) {
        if (i < main) {
            int node = i >> 4;
            int qq = i & 15;
            const float4* src = (const float4*)((node < S_NUM)
                                  ? stu + (size_t)node * KDIM
                                  : exer + (size_t)(node - S_NUM) * KDIM);
            float4 a = src[qq * 2];
            float4 b = src[qq * 2 + 1];
            uint4 o;
            o.x = (uint32_t)f2bf(a.x) | ((uint32_t)f2bf(a.y) << 16);
            o.y = (uint32_t)f2bf(a.z) | ((uint32_t)f2bf(a.w) << 16);
            o.z = (uint32_t)f2bf(b.x) | ((uint32_t)f2bf(b.y) << 16);
            o.w = (uint32_t)f2bf(b.z) | ((uint32_t)f2bf(b.w) << 16);
            featb[i] = o;
        } else if (i < main + 48) {
            int j = i - main;
            size_t off = (size_t)NNODE * 16 + (j & 15);
            switch (j >> 4) {
                case 0: featb[off] = z4; break;
                case 1: fcR[off] = z4; break;
                default: fcW[off] = z4; break;
            }
        } else {
            int k = i - main - 48;
            if (k <= NNODE)  cjpR[k] = (k < NNODE) ? rcj[k] : 0.f;
            else {
                int m = k - (NNODE + 1);
                cjpW[m] = (m < NNODE) ? wcj[m] : 0.f;
            }
        }
    }
}

// ---------------- aggregation, both graphs: 16-lane group = one node ----------------
// lane&15 owns 8 dims (uint4); no cross-lane reduction; rows 16-padded with
// sentinel src NNODE (zero row) -> checkless inner loop. int4 csr loads,
// 16 edges unrolled -> 16 row-gathers in flight per lane.
template<int USECJ, int COMPACT>
__global__ __launch_bounds__(256) void agg2_k(const uint4* __restrict__ srcR,
                                              const uint4* __restrict__ srcW,
                                              const float* __restrict__ cjR,
                                              const float* __restrict__ cjW,
                                              const int* __restrict__ rpb,
                                              const int* __restrict__ rpe,
                                              const int* __restrict__ csr,
                                              const int* __restrict__ list,
                                              const int* __restrict__ nselp,
                                              uint4* __restrict__ outR,
                                              uint4* __restrict__ outW) {
    int lane = threadIdx.x & 63, wid = threadIdx.x >> 6;
    int grp = lane >> 4, c16 = lane & 15;
    int gi = blockIdx.x * 16 + wid * 4 + grp;
    int graph, n, orow;
    if (COMPACT) {
        int nsel = nselp[0];
        graph = gi >= CAPC;
        int ci = graph ? gi - CAPC : gi;
        if (ci >= nsel) return;
        n = list[ci];
        orow = ci;
    } else {
        if (gi >= 2 * NNODE) return;
        graph = gi >= NNODE;
        n = graph ? gi - NNODE : gi;
        orow = n;
    }
    const uint4* fc = graph ? srcW : srcR;
    const float* cjg = graph ? cjW : cjR;
    int beg = (rpb + graph * NNODE)[n];
    int end = (rpe + graph * NNODE)[n];
    uint4* outp = graph ? outW : outR;
    const int4* csr4 = (const int4*)csr;

    f32x2 a0 = {0.f, 0.f}, a1 = {0.f, 0.f}, a2 = {0.f, 0.f}, a3 = {0.f, 0.f};
    int e = beg;
    // 16-deep unrolled main loop (rows padded to mult-16, beg 16-aligned)
    for (; e + 16 <= end; e += 16) {
        int4 sv[4];
        sv[0] = csr4[(e >> 2)];
        sv[1] = csr4[(e >> 2) + 1];
        sv[2] = csr4[(e >> 2) + 2];
        sv[3] = csr4[(e >> 2) + 3];
        int s[16];
        #pragma unroll
        for (int q = 0; q < 4; ++q) {
            s[q * 4 + 0] = sv[q].x; s[q * 4 + 1] = sv[q].y;
            s[q * 4 + 2] = sv[q].z; s[q * 4 + 3] = sv[q].w;
        }
        uint4 u[16];
        #pragma unroll
        for (int j = 0; j < 16; ++j)
            u[j] = fc[(size_t)s[j] * 16 + c16];
        if (USECJ) {
            float w[16];
            #pragma unroll
            for (int j = 0; j < 16; ++j) w[j] = cjg[s[j]];
            #pragma unroll
            for (int j = 0; j < 16; ++j) {
                f32x2 v = {w[j], w[j]};
                a0 += v * up2(u[j].x);
                a1 += v * up2(u[j].y);
                a2 += v * up2(u[j].z);
                a3 += v * up2(u[j].w);
            }
        } else {
            #pragma unroll
            for (int j = 0; j < 16; ++j) {
                a0 += up2(u[j].x);
                a1 += up2(u[j].y);
                a2 += up2(u[j].z);
                a3 += up2(u[j].w);
            }
        }
    }
    uint4 o;
    o.x = pk2(a0); o.y = pk2(a1); o.z = pk2(a2); o.w = pk2(a3);
    outp[(size_t)orow * 16 + c16] = o;
}

// ---------------- fused GEMM, both graphs, 256 rows/block; COMPACT for L3 ----------------
template<int COMPACT>
__global__ __launch_bounds__(256) void gemm2_k(const ushort* __restrict__ AR,
                                               const ushort* __restrict__ AW,
                                               const ushort* __restrict__ wsR,
                                               const ushort* __restrict__ wsW,
                                               const float* __restrict__ rci,
                                               const float* __restrict__ rcj,
                                               const float* __restrict__ wci,
                                               const float* __restrict__ wcj,
                                               const int* __restrict__ list,
                                               const int* __restrict__ nselp,
                                               ushort* __restrict__ outR,
                                               ushort* __restrict__ outW,
                                               int mode) {
    const int halfBlocks = COMPACT ? (CAPC / GR) : ((NNODE + GR - 1) / GR);
    int graph = blockIdx.x >= halfBlocks;
    int bb = graph ? blockIdx.x - halfBlocks : blockIdx.x;
    int nrows = COMPACT ? nselp[0] : NNODE;
    const ushort* A = graph ? AW : AR;
    const ushort* wsm = graph ? wsW : wsR;
    const float* ci = graph ? wci : rci;
    const float* cj = graph ? wcj : rcj;
    ushort* outB = graph ? outW : outR;

    __shared__ ushort wt[32768];   // 64 KB: hi + lo plane, pre-swizzled
    {
        const uint4* g = (const uint4*)wsm;
        uint4* l = (uint4*)wt;
        for (int i = threadIdx.x; i < 4096; i += 256) l[i] = g[i];
    }
    __syncthreads();

    int wid = threadIdx.x >> 6, lane = threadIdx.x & 63;
    int q = lane >> 4, l16 = lane & 15;
    int rbase = bb * GR + wid * 64;
    if (rbase >= nrows) return;

    short8 z8 = {0, 0, 0, 0, 0, 0, 0, 0};
    short8 afr[4][4];
    #pragma unroll
    for (int t = 0; t < 4; ++t) {
        int row = rbase + t * 16 + l16;
        bool rok = row < nrows;
        const short8* ar = (const short8*)(A + (size_t)row * KDIM);
        #pragma unroll
        for (int kb = 0; kb < 4; ++kb)
            afr[t][kb] = rok ? ar[kb * 4 + q] : z8;
    }
    float scal[4][4];
    #pragma unroll
    for (int t = 0; t < 4; ++t)
        #pragma unroll
        for (int b = 0; b < 4; ++b) {
            int r = rbase + t * 16 + q * 4 + b;
            bool ok = r < nrows;
            int node = COMPACT ? (ok ? list[r] : 0) : r;
            scal[t][b] = ok ? (mode ? ci[node] * cj[node] : ci[node]) : 0.f;
        }

    #pragma unroll
    for (int cb = 0; cb < 8; ++cb) {
        int c = cb * 16 + l16;
        short8 bHi[4], bLo[4];
        #pragma unroll
        for (int kb = 0; kb < 4; ++kb) {
            int byte = (c * 256 + 2 * (kb * 32 + q * 8)) ^ ((c & 7) << 4);
            bHi[kb] = *(const short8*)((const char*)wt + byte);
            bLo[kb] = *(const short8*)((const char*)wt + 32768 + byte);
        }
        #pragma unroll
        for (int t = 0; t < 4; ++t) {
            f32x4 acc = {0.f, 0.f, 0.f, 0.f};
            #pragma unroll
            for (int kb = 0; kb < 4; ++kb) {
                acc = __builtin_amdgcn_mfma_f32_16x16x32_bf16(afr[t][kb], bHi[kb], acc, 0, 0, 0);
                acc = __builtin_amdgcn_mfma_f32_16x16x32_bf16(afr[t][kb], bLo[kb], acc, 0, 0, 0);
            }
            #pragma unroll
            for (int b = 0; b < 4; ++b) {
                int r = rbase + t * 16 + q * 4 + b;
                if (r < nrows)
                    outB[(size_t)r * KDIM + c] = f2bf(acc[b] * scal[t][b]);
            }
        }
    }
}

// ---------------- output assembly (compacted w1c/w2c bf16 -> f32 out) ----------------
__global__ void out_k(const ushort* __restrict__ w1c, const ushort* __restrict__ w2c,
                      const int* __restrict__ inv,
                      const float* __restrict__ disc, const float* __restrict__ kn,
                      const int* __restrict__ sid, const int* __restrict__ eid,
                      float* __restrict__ out) {
    const int total = 2 * BATCH * KDIM + BATCH + KDIM * KDIM;
    for (int i = blockIdx.x * blockDim.x + threadIdx.x; i < total;
         i += gridDim.x * blockDim.x) {
        if (i < BATCH * KDIM) {
            int b = i >> 7, c = i & 127;
            size_t r = (size_t)inv[sid[b]];
            out[i] = bf2f(w1c[r * KDIM + c]) + bf2f(w2c[r * KDIM + c]);
        } else if (i < 2 * BATCH * KDIM) {
            int j = i - BATCH * KDIM;
            int b = j >> 7, c = j & 127;
            size_t r = (size_t)inv[S_NUM + eid[b]];
            out[i] = bf2f(w1c[r * KDIM + c]) + bf2f(w2c[r * KDIM + c]);
        } else if (i < 2 * BATCH * KDIM + BATCH) {
            out[i] = disc[eid[i - 2 * BATCH * KDIM]];
        } else {
            out[i] = kn[i - (2 * BATCH * KDIM + BATCH)];
        }
    }
}

static inline size_t align_up(size_t x) { return (x + 255) & ~(size_t)255; }

extern "C" void kernel_launch(void* const* d_in, const int* in_sizes, int n_in,
                              void* d_out, int out_size, void* d_ws, size_t ws_size,
                              hipStream_t stream) {
    const float* stu  = (const float*)d_in[0];
    const float* exer = (const float*)d_in[1];
    const float* kn   = (const float*)d_in[2];
    const float* disc = (const float*)d_in[3];
    const float* rW   = (const float*)d_in[4];
    const float* wW   = (const float*)d_in[5];
    const float* rci  = (const float*)d_in[6];
    const float* rcj  = (const float*)d_in[7];
    const float* wci  = (const float*)d_in[8];
    const float* wcj  = (const float*)d_in[9];
    const int* redge   = (const int*)d_in[10];
    const int* wedge   = (const int*)d_in[11];
    const int* sid     = (const int*)d_in[12];
    const int* eid     = (const int*)d_in[13];
    float* out         = (float*)d_out;

    char* p = (char*)d_ws;
    const size_t fB16 = align_up((size_t)(NNODE + 1) * KDIM * 2);   // +sentinel row
    ushort* featb = (ushort*)p; p += fB16;  // L1 gather src; later w1c/w2c (compact, 8MB)
    ushort* fcR = (ushort*)p; p += fB16;
    ushort* fcW = (ushort*)p; p += fB16;
    ushort* pR  = (ushort*)p; p += fB16;    // agg out; aliases buckets pre-L1
    ushort* pW  = (ushort*)p; p += fB16;
    ushort* ws  = (ushort*)p; p += align_up((size_t)6 * 32768 * 2);   // 384 KB
    int* gbcnt = (int*)p; p += align_up((size_t)256 * 4);
    int* rpb = (int*)p; p += align_up((size_t)2 * NNODE * 4);
    int* rpe = (int*)p; p += align_up((size_t)2 * NNODE * 4);
    int* csr = (int*)p; p += align_up((size_t)256 * RCAP * 4);
    float* cjpR = (float*)p; p += align_up((size_t)(NNODE + 1) * 4);
    float* cjpW = (float*)p; p += align_up((size_t)(NNODE + 1) * 4);
    int* flags = (int*)p; p += align_up((size_t)NNODE * 4);
    int* list  = (int*)p; p += align_up((size_t)CAPC * 4);
    int* inv   = (int*)p; p += align_up((size_t)NNODE * 4);
    int* nsel  = (int*)p; p += align_up((size_t)16 * 4);
    // buckets alias pR (256 x 8448 x 4B = 8.65 MB < 17.92 MB)
    uint32_t* bpk = (uint32_t*)pR;
    // compact outputs alias featb (2 x 16384 x 128 x 2B = 8 MB < 17.92 MB)
    ushort* w1c = featb;
    ushort* w2c = featb + (size_t)CAPC * KDIM;

    const int aggFull = (2 * NNODE + 15) / 16;      // 8750
    const int aggComp = 2 * CAPC / 16;              // 2048
    const int gemmFull = 2 * ((NNODE + GR - 1) / GR);
    const int gemmComp = 2 * (CAPC / GR);
    const int NB = (NEDGE + CHUNK - 1) / CHUNK;

    // ---- shared prep ----
    prepW_k<<<(6 * 16384 + 255) / 256, 256, 0, stream>>>(rW, wW, ws, gbcnt, flags, nsel);
    bucket_k<<<2 * NB, 256, 0, stream>>>(redge, wedge, gbcnt, bpk);
    build_k<<<256, 256, 0, stream>>>(bpk, gbcnt, rpb, rpe, csr);
    markcompact_k<<<(2 * BATCH + 255) / 256, 256, 0, stream>>>(sid, eid, flags, list, inv, nsel);
    cvt1_k<<<2048, 256, 0, stream>>>(stu, exer, rcj, wcj, (uint4*)featb,
                                     (uint4*)fcR, (uint4*)fcW, cjpR, cjpW);

    // ---- L1 (full) ----
    agg2_k<1, 0><<<aggFull, 256, 0, stream>>>((const uint4*)featb, (const uint4*)featb,
                                              cjpR, cjpW, rpb, rpe, csr, nullptr, nullptr,
                                              (uint4*)pR, (uint4*)pW);
    gemm2_k<0><<<gemmFull, 256, 0, stream>>>(pR, pW, ws + 0 * 32768, ws + 3 * 32768,
                                             rci, rcj, wci, wcj, nullptr, nullptr,
                                             fcR, fcW, 1);
    // ---- L2 (full) ----
    agg2_k<0, 0><<<aggFull, 256, 0, stream>>>((const uint4*)fcR, (const uint4*)fcW,
                                              nullptr, nullptr, rpb, rpe, csr,
                                              nullptr, nullptr, (uint4*)pR, (uint4*)pW);
    gemm2_k<0><<<gemmFull, 256, 0, stream>>>(pR, pW, ws + 1 * 32768, ws + 4 * 32768,
                                             rci, rcj, wci, wcj, nullptr, nullptr,
                                             fcR, fcW, 1);
    // ---- L3 (compact: only nodes the output reads) ----
    agg2_k<0, 1><<<aggComp, 256, 0, stream>>>((const uint4*)fcR, (const uint4*)fcW,
                                              nullptr, nullptr, rpb, rpe, csr,
                                              list, nsel, (uint4*)pR, (uint4*)pW);
    gemm2_k<1><<<gemmComp, 256, 0, stream>>>(pR, pW, ws + 2 * 32768, ws + 5 * 32768,
                                             rci, rcj, wci, wcj, list, nsel,
                                             w1c, w2c, 0);

    out_k<<<2048, 256, 0, stream>>>(w1c, w2c, inv, disc, kn, sid, eid, out);
}